// Round 5
// baseline (2456.311 us; speedup 1.0000x reference)
//
#include <hip/hip_runtime.h>
#include <math.h>

// OptNet batched QP IPM solver — Round 11 resubmitted unchanged after an
// infrastructure failure ("MI355X container failed twice", no kernel signal;
// same transient mode as two prior incidents, both cleared on resubmission).
// R10 lesson: intervals cost ~7us dispatch-time each regardless of payload
// (R8: D875us/D126 intervals); sweep halved intervals but doubled factor
// FLOPs = wash. This round deletes ~53 intervals with ZERO added FLOPs:
//  * wz-combine + g1-combine phases inlined at consumers (split-k partials
//    summed in-place; g1 partials moved to scr[512..768) to avoid racing
//    wz partials in scr[0..512)); identical summation order.
//  * corrector solve skips t & H phases (H = rs/d and H1 = 0 precomputed in
//    the non_zero phase); solve barriers 7/6 -> 5/3.
//  * alpha_aff+sigma fused; alpha2+state-update fused; min/shift fused
//    (wave-0 in-wave __shfl broadcast, no LDS round-trip).
//  * factor_S trailing sync dropped (next W-upper read is >=2 barriers away).
//  * t1 = V^T G^T reads G rows straight from global (no LDS staging): -8.
// Intervals ~245 -> ~192. Sweep factorization (R10, verified) untouched.

#define NT  512
#define WST 130    // factor stride: 130 % 32 = 2 -> 2-way column conflicts (free)
#define T1O 4352   // t1 = V_Q^T G^T (64 x 128) offset inside W
#define T1S 132

struct __align__(16) Smem {
  float W[16640];     // 66560 B: upper = factor / M^{-1}; strictly-lower = R
  float scr[2048];    // union: sweep/chol panels (2x1024) / split-k partials
  float x[64], rxv[64], g1[64], t[64], dxa[64];
  float s[128], z[128], rz[128], dsa[128], dza[128], u12[128], dd[128], H[128], Y[128];
  float Rdiag[128];   // R's diagonal (lower triangle of W can't hold it)
  float scalbuf[64];  // Q-path: [0,16) 2x8 inv-diags | sweep: [16,62) 2x2x10
  float scal[16];
};
static_assert(sizeof(Smem) <= 81920, "LDS must fit 2 blocks/CU");

enum { SC_H1 = 2, SC_U11I = 4, SC_RY = 5, SC_MU = 6,
       SC_MUSIG = 8, SC_Y = 9, SC_DYA = 10, SC_WY = 11 };

__device__ __forceinline__ float wred_sum(float v) {
#pragma unroll
  for (int off = 32; off > 0; off >>= 1) v += __shfl_down(v, off);
  return v;
}
__device__ __forceinline__ float wred_min(float v) {
#pragma unroll
  for (int off = 32; off > 0; off >>= 1) v = fminf(v, __shfl_down(v, off));
  return v;
}
__device__ __forceinline__ float step_val(float v, float dv) {
  float a = -v / dv;
  return (a > 0.0f) ? a : __builtin_inff();  // NaN -> inf (matches ref)
}
__device__ __forceinline__ constexpr int pk16(int i) {  // packed 16x16 upper row start
  return i * 16 - ((i * (i - 1)) >> 1);
}

// ======================= Q-path (64x64) machinery — unchanged ==============

template<int RW>
__device__ __forceinline__ void elim_publish(Smem& sm, float (&Wt)[4][8],
                                             int q, int tc) {
  const int tcd = q >> 1;
  const int co = (q & 1) << 2;
  float L10 = 0, L20 = 0, L30 = 0, L21 = 0, L31 = 0, L32 = 0;
  float id0 = 0, id1 = 0, id2 = 0, id3 = 0;
  if (tc == tcd) {
    float D[4][4];
#pragma unroll
    for (int m = 0; m < 4; ++m)
#pragma unroll
      for (int c = 0; c < 4; ++c) D[m][c] = Wt[m][co + c];
    id0 = 1.0f / D[0][0];
    L10 = D[0][1] * id0; L20 = D[0][2] * id0; L30 = D[0][3] * id0;
#pragma unroll
    for (int c = 0; c < 4; ++c) {
      D[1][c] -= L10 * D[0][c]; D[2][c] -= L20 * D[0][c]; D[3][c] -= L30 * D[0][c];
    }
    id1 = 1.0f / D[1][1];
    L21 = D[1][2] * id1; L31 = D[1][3] * id1;
#pragma unroll
    for (int c = 0; c < 4; ++c) { D[2][c] -= L21 * D[1][c]; D[3][c] -= L31 * D[1][c]; }
    id2 = 1.0f / D[2][2];
    L32 = D[2][3] * id2;
#pragma unroll
    for (int c = 0; c < 4; ++c) D[3][c] -= L32 * D[2][c];
    id3 = 1.0f / D[3][3];
  }
  const int src = ((q & 3) << 4) + tcd;
  L10 = __shfl(L10, src); L20 = __shfl(L20, src); L30 = __shfl(L30, src);
  L21 = __shfl(L21, src); L31 = __shfl(L31, src); L32 = __shfl(L32, src);
#pragma unroll
  for (int c = 0; c < 8; ++c) {
    Wt[1][c] = fmaf(-L10, Wt[0][c], Wt[1][c]);
    Wt[2][c] = fmaf(-L20, Wt[0][c], Wt[2][c]);
    Wt[2][c] = fmaf(-L21, Wt[1][c], Wt[2][c]);
    Wt[3][c] = fmaf(-L30, Wt[0][c], Wt[3][c]);
    Wt[3][c] = fmaf(-L31, Wt[1][c], Wt[3][c]);
    Wt[3][c] = fmaf(-L32, Wt[2][c], Wt[3][c]);
  }
  const int pb = (q >> 1) & 1;
  float* pp = sm.scr + pb * (8 * RW) + (q & 1) * (4 * RW);
  const int j0 = tc << 3;
#pragma unroll
  for (int m = 0; m < 4; ++m) {
    *(float4*)&pp[m * RW + j0]     = make_float4(Wt[m][0], Wt[m][1], Wt[m][2], Wt[m][3]);
    *(float4*)&pp[m * RW + j0 + 4] = make_float4(Wt[m][4], Wt[m][5], Wt[m][6], Wt[m][7]);
  }
  if (tc == tcd) {
    float* sb = sm.scalbuf + pb * 8 + ((q & 1) << 2);
    sb[0] = id0; sb[1] = id1; sb[2] = id2; sb[3] = id3;
    sm.Y[(q << 2) + 0] = id0; sm.Y[(q << 2) + 1] = id1;
    sm.Y[(q << 2) + 2] = id2; sm.Y[(q << 2) + 3] = id3;
  }
}

template<int RW>
__device__ __forceinline__ void apply_panel4(Smem& sm, float (&Wt)[4][8],
                                             int pb, int half, int i0, int j0) {
  const float* pp = sm.scr + pb * (8 * RW) + half * (4 * RW);
  const float* sb = sm.scalbuf + pb * 8 + (half << 2);
#pragma unroll 1
  for (int mm = 0; mm < 4; ++mm) {
    const float idm = sb[mm];
    const float4 pv  = *(const float4*)&pp[mm * RW + i0];
    const float4 pj0 = *(const float4*)&pp[mm * RW + j0];
    const float4 pj1 = *(const float4*)&pp[mm * RW + j0 + 4];
    const float um0 = pv.x * idm, um1 = pv.y * idm;
    const float um2 = pv.z * idm, um3 = pv.w * idm;
    const float pjv[8] = {pj0.x, pj0.y, pj0.z, pj0.w, pj1.x, pj1.y, pj1.z, pj1.w};
#pragma unroll
    for (int c = 0; c < 8; ++c) {
      Wt[0][c] = fmaf(-um0, pjv[c], Wt[0][c]);
      Wt[1][c] = fmaf(-um1, pjv[c], Wt[1][c]);
      Wt[2][c] = fmaf(-um2, pjv[c], Wt[2][c]);
      Wt[3][c] = fmaf(-um3, pjv[c], Wt[3][c]);
    }
  }
}

template<int N, int RW, int ST>
__device__ void chol_rank8(Smem& sm, float (&Wt)[4][8], int act, int tid) {
  const int tr = tid >> 4, tc = tid & 15;
  const int i0 = tr << 2, j0 = tc << 3;
  constexpr int NP = N / 8;
#pragma unroll 1
  for (int P = 0; P < NP; ++P) {
    const int pb = P & 1;
    if (P > 0 && act && tr >= 2 * P) {
      apply_panel4<RW>(sm, Wt, pb ^ 1, 0, i0, j0);
      apply_panel4<RW>(sm, Wt, pb ^ 1, 1, i0, j0);
    }
    if ((tid >> 6) == (P >> 1)) {
      if (act && tr == 2 * P) elim_publish<RW>(sm, Wt, 2 * P, tc);
      __threadfence_block();
      if (act && tr == 2 * P + 1) {
        apply_panel4<RW>(sm, Wt, pb, 0, i0, j0);
        elim_publish<RW>(sm, Wt, 2 * P + 1, tc);
      }
    }
    __syncthreads();
  }
}

template<int ST>
__device__ __forceinline__ void write_U(Smem& sm, float (&Wt)[4][8], int act,
                                        int i0, int j0) {
  if (act && j0 + 7 >= i0) {
    float sqv[4];
#pragma unroll
    for (int m = 0; m < 4; ++m) sqv[m] = sqrtf(sm.Y[i0 + m]);
    if (j0 >= i0 + 3) {
#pragma unroll
      for (int m = 0; m < 4; ++m)
#pragma unroll
        for (int qq = 0; qq < 4; ++qq)
          *(float2*)&sm.W[(i0 + m) * ST + j0 + 2 * qq] =
              make_float2(Wt[m][2 * qq] * sqv[m], Wt[m][2 * qq + 1] * sqv[m]);
    } else {
#pragma unroll
      for (int m = 0; m < 4; ++m) {
        const int i = i0 + m;
#pragma unroll
        for (int c = 0; c < 8; ++c) {
          const int j = j0 + c;
          if (j >= i) sm.W[i * ST + j] = Wt[m][c] * sqv[m];
        }
      }
    }
  }
}

template<int N, int ST>
__device__ void trtri_fast(Smem& sm, int tid) {
  constexpr int NB = N >> 4;
  if (tid < NB * 16) {
    const int blk = tid >> 4, c = tid & 15;
    const float* D = sm.W + (blk << 4) * ST + (blk << 4);
    float vv[16];
#pragma unroll
    for (int i = 15; i >= 0; --i) {
      float acc = 0.0f;
      for (int k = i + 1; k < 16; ++k) acc += D[i * ST + k] * vv[k];
      const float di = D[i * ST + i];
      const float val = (i == c) ? (1.0f / di) : (-acc / di);
      vv[i] = (i <= c) ? val : 0.0f;
    }
#pragma unroll
    for (int i = 0; i < 16; ++i)
      if (i <= c) sm.scr[blk * 136 + pk16(i) + (c - i)] = vv[i];
  }
  __syncthreads();
  constexpr int NROWS = 16 * (NB * (NB - 1) / 2);
  if (tid < NROWS) {
    int J = 1, base = 0;
    while (base + 16 * J <= tid) { base += 16 * J; ++J; }
    const int k = tid - base, Jb = J << 4;
    float u[16], o[16];
    float2* wr = (float2*)&sm.W[k * ST + Jb];
#pragma unroll
    for (int q = 0; q < 8; ++q) { const float2 v = wr[q]; u[2*q] = v.x; u[2*q+1] = v.y; }
    const float* vd = sm.scr + J * 136;
#pragma unroll
    for (int c = 0; c < 16; ++c) {
      float acc = 0.0f;
#pragma unroll
      for (int jj = 0; jj <= c; ++jj) acc += u[jj] * vd[pk16(jj) + (c - jj)];
      o[c] = acc;
    }
#pragma unroll
    for (int q = 0; q < 8; ++q) wr[q] = make_float2(o[2*q], o[2*q+1]);
  } else {
    for (int idx = tid - NROWS; idx < 256; idx += NT - NROWS) {
      const int r = idx >> 4, c2 = idx & 15;
      if (c2 >= r) sm.W[r * ST + c2] = sm.scr[pk16(r) + (c2 - r)];
    }
  }
  for (int J = 1; J < NB; ++J) {
    __syncthreads();
    const int Jb = J << 4;
    const int nStrip = Jb << 2;
    float acc[4] = {0.0f, 0.0f, 0.0f, 0.0f};
    int wi = 0, wc = 0;
    if (tid < nStrip) {
      wi = tid >> 2; wc = (tid & 3) << 2;
      for (int k = wi; k < Jb; ++k) {
        const float v = sm.W[wi * ST + k];
        const float2 u0 = *(const float2*)&sm.W[k * ST + Jb + wc];
        const float2 u1 = *(const float2*)&sm.W[k * ST + Jb + wc + 2];
        acc[0] = fmaf(v, u0.x, acc[0]); acc[1] = fmaf(v, u0.y, acc[1]);
        acc[2] = fmaf(v, u1.x, acc[2]); acc[3] = fmaf(v, u1.y, acc[3]);
      }
      acc[0] = -acc[0]; acc[1] = -acc[1]; acc[2] = -acc[2]; acc[3] = -acc[3];
    } else if (tid < nStrip + 64) {
      const int l = tid - nStrip;
      const int r = l >> 2; wi = Jb + r; wc = (l & 3) << 2;
      const float* vp = sm.scr + J * 136 + pk16(r) - r;
#pragma unroll
      for (int q = 0; q < 4; ++q) {
        const int c = wc + q;
        acc[q] = (c >= r) ? vp[c] : 0.0f;
      }
    }
    __syncthreads();
    if (tid < nStrip) {
      *(float2*)&sm.W[wi * ST + Jb + wc]     = make_float2(acc[0], acc[1]);
      *(float2*)&sm.W[wi * ST + Jb + wc + 2] = make_float2(acc[2], acc[3]);
    } else if (tid < nStrip + 64) {
      const int r = wi - Jb;
#pragma unroll
      for (int q = 0; q < 4; ++q)
        if (wc + q >= r) sm.W[wi * ST + Jb + wc + q] = acc[q];
    }
  }
  __syncthreads();
}

// ======================= 128-factor: symmetric SWEEP (R10, verified) =======

__device__ __forceinline__ void elim_sweep(Smem& sm, float (&Wt)[4][8],
                                           int q, int tc) {
  const int tcd = q >> 1;
  const int co = (q & 1) << 2;
  float L10 = 0, L20 = 0, L30 = 0, L21 = 0, L31 = 0, L32 = 0;
  float id0 = 0, id1 = 0, id2 = 0, id3 = 0;
  if (tc == tcd) {
    float D[4][4];
#pragma unroll
    for (int m = 0; m < 4; ++m)
#pragma unroll
      for (int c = 0; c < 4; ++c) D[m][c] = Wt[m][co + c];
    id0 = 1.0f / D[0][0];
    L10 = D[0][1] * id0; L20 = D[0][2] * id0; L30 = D[0][3] * id0;
#pragma unroll
    for (int c = 0; c < 4; ++c) {
      D[1][c] -= L10 * D[0][c]; D[2][c] -= L20 * D[0][c]; D[3][c] -= L30 * D[0][c];
    }
    id1 = 1.0f / D[1][1];
    L21 = D[1][2] * id1; L31 = D[1][3] * id1;
#pragma unroll
    for (int c = 0; c < 4; ++c) { D[2][c] -= L21 * D[1][c]; D[3][c] -= L31 * D[1][c]; }
    id2 = 1.0f / D[2][2];
    L32 = D[2][3] * id2;
#pragma unroll
    for (int c = 0; c < 4; ++c) D[3][c] -= L32 * D[2][c];
    id3 = 1.0f / D[3][3];
  }
  const int src = ((q & 3) << 4) + tcd;
  L10 = __shfl(L10, src); L20 = __shfl(L20, src); L30 = __shfl(L30, src);
  L21 = __shfl(L21, src); L31 = __shfl(L31, src); L32 = __shfl(L32, src);
  id0 = __shfl(id0, src); id1 = __shfl(id1, src);
  id2 = __shfl(id2, src); id3 = __shfl(id3, src);
#pragma unroll
  for (int c = 0; c < 8; ++c) {  // own rows -> F_raw = L^{-1} * rows
    Wt[1][c] = fmaf(-L10, Wt[0][c], Wt[1][c]);
    Wt[2][c] = fmaf(-L20, Wt[0][c], Wt[2][c]);
    Wt[2][c] = fmaf(-L21, Wt[1][c], Wt[2][c]);
    Wt[3][c] = fmaf(-L30, Wt[0][c], Wt[3][c]);
    Wt[3][c] = fmaf(-L31, Wt[1][c], Wt[3][c]);
    Wt[3][c] = fmaf(-L32, Wt[2][c], Wt[3][c]);
  }
  const int pb = (q >> 1) & 1;
  float* pp = sm.scr + pb * 1024 + (q & 1) * 512;
  const int j0 = tc << 3;
#pragma unroll
  for (int m = 0; m < 4; ++m) {   // publish F_raw (pre-back-sub) panel
    *(float4*)&pp[m * 128 + j0]     = make_float4(Wt[m][0], Wt[m][1], Wt[m][2], Wt[m][3]);
    *(float4*)&pp[m * 128 + j0 + 4] = make_float4(Wt[m][4], Wt[m][5], Wt[m][6], Wt[m][7]);
  }
  if (tc == tcd) {
    float* sb = sm.scalbuf + 16 + pb * 24 + (q & 1) * 12;
    sb[0] = id0; sb[1] = id1; sb[2] = id2; sb[3] = id3;
    sb[4] = L10; sb[5] = L20; sb[6] = L30; sb[7] = L21; sb[8] = L31; sb[9] = L32;
  }
  // own rows -> P^{-1}B = L^{-T} D^{-1} F (back-substitution, per column)
#pragma unroll
  for (int c = 0; c < 8; ++c) {
    const float t3 = id3 * Wt[3][c];
    const float t2 = id2 * Wt[2][c] - L32 * t3;
    const float t1v = id1 * Wt[1][c] - L21 * t2 - L31 * t3;
    const float t0 = id0 * Wt[0][c] - L10 * t1v - L20 * t2 - L30 * t3;
    Wt[0][c] = t0; Wt[1][c] = t1v; Wt[2][c] = t2; Wt[3][c] = t3;
  }
  if (tc == tcd) {  // pivot 4x4 <- -P^{-1} = -(L^{-1})^T D^{-1} L^{-1}
    const float m10 = -L10, m21 = -L21, m32 = -L32;
    const float m20 = -L20 + L21 * L10;
    const float m31 = -L31 + L32 * L21;
    const float m30 = -L30 + L31 * L10 + L32 * L20 - L32 * L21 * L10;
    const float P00 = id0 + id1*m10*m10 + id2*m20*m20 + id3*m30*m30;
    const float P01 = id1*m10 + id2*m20*m21 + id3*m30*m31;
    const float P02 = id2*m20 + id3*m30*m32;
    const float P03 = id3*m30;
    const float P11 = id1 + id2*m21*m21 + id3*m31*m31;
    const float P12 = id2*m21 + id3*m31*m32;
    const float P13 = id3*m31;
    const float P22 = id2 + id3*m32*m32;
    const float P23 = id3*m32;
    const float P33 = id3;
    Wt[0][co+0] = -P00; Wt[0][co+1] = -P01; Wt[0][co+2] = -P02; Wt[0][co+3] = -P03;
    Wt[1][co+0] = -P01; Wt[1][co+1] = -P11; Wt[1][co+2] = -P12; Wt[1][co+3] = -P13;
    Wt[2][co+0] = -P02; Wt[2][co+1] = -P12; Wt[2][co+2] = -P22; Wt[2][co+3] = -P23;
    Wt[3][co+0] = -P03; Wt[3][co+1] = -P13; Wt[3][co+2] = -P23; Wt[3][co+3] = -P33;
  }
}

__device__ __forceinline__ void apply_sweep(Smem& sm, float (&Wt)[4][8],
                                            int q, int i0, int j0, int tr, int tc,
                                            int skip_partner) {
  if (tr == q) return;  // own panel: rows already replaced at elim time
  if (skip_partner && !(q & 1) && tr == q + 1) return;
  const int pb = (q >> 1) & 1;
  const float* pp = sm.scr + pb * 1024 + (q & 1) * 512;
  const float* sb = sm.scalbuf + 16 + pb * 24 + (q & 1) * 12;
#pragma unroll 1
  for (int mm = 0; mm < 4; ++mm) {
    const float idm = sb[mm];
    const float4 pv  = *(const float4*)&pp[mm * 128 + i0];
    const float4 pj0 = *(const float4*)&pp[mm * 128 + j0];
    const float4 pj1 = *(const float4*)&pp[mm * 128 + j0 + 4];
    const float um0 = pv.x * idm, um1 = pv.y * idm;
    const float um2 = pv.z * idm, um3 = pv.w * idm;
    const float pjv[8] = {pj0.x, pj0.y, pj0.z, pj0.w, pj1.x, pj1.y, pj1.z, pj1.w};
#pragma unroll
    for (int c = 0; c < 8; ++c) {
      Wt[0][c] = fmaf(-um0, pjv[c], Wt[0][c]);
      Wt[1][c] = fmaf(-um1, pjv[c], Wt[1][c]);
      Wt[2][c] = fmaf(-um2, pjv[c], Wt[2][c]);
      Wt[3][c] = fmaf(-um3, pjv[c], Wt[3][c]);
    }
  }
  if (tc == (q >> 1)) {  // pivot-column cells: (P^{-1}B)[:, i] via back-sub
    const int co = (q & 1) << 2;
    const float id0 = sb[0], id1 = sb[1], id2 = sb[2], id3 = sb[3];
    const float L10 = sb[4], L20 = sb[5], L30 = sb[6];
    const float L21 = sb[7], L31 = sb[8], L32 = sb[9];
#pragma unroll
    for (int r = 0; r < 4; ++r) {
      const float f0 = pp[0 * 128 + i0 + r];
      const float f1 = pp[1 * 128 + i0 + r];
      const float f2 = pp[2 * 128 + i0 + r];
      const float f3 = pp[3 * 128 + i0 + r];
      const float t3 = id3 * f3;
      const float t2 = id2 * f2 - L32 * t3;
      const float t1v = id1 * f1 - L21 * t2 - L31 * t3;
      const float t0 = id0 * f0 - L10 * t1v - L20 * t2 - L30 * t3;
      Wt[r][co+0] = t0; Wt[r][co+1] = t1v; Wt[r][co+2] = t2; Wt[r][co+3] = t3;
    }
  }
}

__device__ void sweep128(Smem& sm, float (&Wt)[4][8], int tid) {
  const int tr = tid >> 4, tc = tid & 15;
  const int i0 = tr << 2, j0 = tc << 3;
#pragma unroll 1
  for (int P = 0; P < 16; ++P) {
    if (P > 0) {
      apply_sweep(sm, Wt, 2 * P - 2, i0, j0, tr, tc, 1);
      apply_sweep(sm, Wt, 2 * P - 1, i0, j0, tr, tc, 1);
    }
    if ((tid >> 6) == (P >> 1)) {
      if (tr == 2 * P) elim_sweep(sm, Wt, 2 * P, tc);
      __threadfence_block();
      if (tr == 2 * P + 1) {
        apply_sweep(sm, Wt, 2 * P, i0, j0, tr, tc, 0);
        elim_sweep(sm, Wt, 2 * P + 1, tc);
      }
    }
    __syncthreads();
  }
  apply_sweep(sm, Wt, 30, i0, j0, tr, tc, 1);
  apply_sweep(sm, Wt, 31, i0, j0, tr, tc, 1);
}

// ---- factor S = R + diag + eps; leaves M^{-1} in W's upper triangle.
// NOTE: no trailing sync — the first W-upper read after the writeback is
// >= 2 barriers away (solve's t/H or nonzero phases). ----
__device__ void factor_S(Smem& sm, int init, int tid) {
  const int tr = tid >> 4, tc = tid & 15;
  const int i0 = tr << 2, j0 = tc << 3;
  float Wt[4][8];
#pragma unroll
  for (int m = 0; m < 4; ++m) {
    const int i = i0 + m;
#pragma unroll
    for (int c = 0; c < 8; ++c) {
      const int j = j0 + c;
      float v;
      if (i < j)      v = sm.W[j * WST + i];
      else if (i > j) v = sm.W[i * WST + j];
      else            v = sm.Rdiag[i] + (init ? 1.0f : sm.s[i] / sm.z[i]) + 1e-6f;
      Wt[m][c] = v;
    }
  }
  sweep128(sm, Wt, tid);
  if (j0 + 7 >= i0) {
    if (j0 >= i0 + 3) {
#pragma unroll
      for (int m = 0; m < 4; ++m)
#pragma unroll
        for (int qq = 0; qq < 4; ++qq)
          *(float2*)&sm.W[(i0 + m) * WST + j0 + 2 * qq] =
              make_float2(-Wt[m][2 * qq], -Wt[m][2 * qq + 1]);
    } else {
#pragma unroll
      for (int m = 0; m < 4; ++m) {
        const int i = i0 + m;
#pragma unroll
        for (int c = 0; c < 8; ++c) {
          const int j = j0 + c;
          if (j >= i) sm.W[i * WST + j] = -Wt[m][c];
        }
      }
    }
  }
}

// ---- KKT solve. has_rx=0 (corrector): t & H phases skipped — H and SC_H1
// must be pre-filled by the caller. wz/g1 split-k partials are inlined at
// consumers (no combine phases). Barriers: 5 (full) / 3 (light). ----
__device__ void solve_kkt(Smem& sm, const float* qreg, const float* Gb, const float* Ab,
                          int has_rx, const float* rx, const float* rs,
                          int has_rz, const float* rz, float ry,
                          float* dx_t, float* ds_t, float* dz_t, int dy_slot,
                          int accum, int tid) {
  const float u11i = sm.scal[SC_U11I];
  const int o8 = tid >> 3, seg = tid & 7;
  if (has_rx) {
    {  // t = Qinv rx via register Qi + 8-lane shfl reduce
      float acc = 0.0f;
#pragma unroll
      for (int c = 0; c < 8; ++c) acc += qreg[c] * rx[seg * 8 + c];
      acc += __shfl_down(acc, 4); acc += __shfl_down(acc, 2); acc += __shfl_down(acc, 1);
      if (seg == 0) sm.t[o8] = acc;
    }
    __syncthreads();
    {  // H = G t + rs/d - rz  (float4 row dots) + fused H1 = a.t - ry
      const int i = tid >> 2, q = tid & 3;
      float acc = 0.0f;
      const float* gr = Gb + (i << 6) + (q << 4);
#pragma unroll
      for (int kk = 0; kk < 16; kk += 4) {
        const float4 g4 = *(const float4*)(gr + kk);
        const float4 t4 = *(const float4*)&sm.t[(q << 4) + kk];
        acc += g4.x * t4.x + g4.y * t4.y + g4.z * t4.z + g4.w * t4.w;
      }
      float h1v = (tid < 64) ? Ab[tid] * sm.t[tid] : 0.0f;
      h1v = wred_sum(h1v);  // meaningful in wave 0 only
      acc += __shfl_down(acc, 2); acc += __shfl_down(acc, 1);
      if (q == 0) {
        if (rs) acc += rs[i] / sm.dd[i];
        if (has_rz) acc -= rz[i];
        sm.H[i] = acc;
      }
      if (tid == 0) sm.scal[SC_H1] = h1v - ry;
    }
    __syncthreads();
  }
  const float y1 = sm.scal[SC_H1] * u11i;
  {  // wz partials = Minv (H - u12 y1): symmetric matvec, 4-way split-k
    const int o = tid & 127, p = tid >> 7;
    float acc = 0.0f;
    for (int k = (p << 5); k < (p << 5) + 32; ++k) {
      const int lo = (k < o) ? k : o;
      const int hi = (k < o) ? o : k;
      acc += sm.W[lo * WST + hi] * (sm.H[k] - sm.u12[k] * y1);
    }
    sm.scr[(p << 7) + o] = acc;
  }
  __syncthreads();
  // FUSED: g1 partials (tid<256, wz inlined — scr reads are wave-uniform
  // broadcasts) | ds,dz (256..384) | w_y (wave 6). g1 partials -> scr[512..)
  if (tid < 256) {
    const int o = tid & 63, p = tid >> 6;
    float acc = 0.0f;
    for (int i = (p << 5); i < (p << 5) + 32; ++i) {
      const float wzv = -(sm.scr[i] + sm.scr[128 + i] + sm.scr[256 + i] + sm.scr[384 + i]);
      acc -= Gb[(i << 6) + o] * wzv;
    }
    sm.scr[512 + (p << 6) + o] = acc;
  } else if (tid < 384) {
    const int i = tid - 256;
    const float wzv = -(sm.scr[i] + sm.scr[128 + i] + sm.scr[256 + i] + sm.scr[384 + i]);
    const float r = rs ? rs[i] : 0.0f;
    const float dsv = (-r - wzv) / sm.dd[i];
    if (accum) { ds_t[i] += dsv; dz_t[i] += wzv; }
    else       { ds_t[i] = dsv;  dz_t[i] = wzv; }
  } else if (tid < 448) {
    const int l = tid - 384;
    const float wa = -(sm.scr[l] + sm.scr[128 + l] + sm.scr[256 + l] + sm.scr[384 + l]);
    const int l2 = l + 64;
    const float wb = -(sm.scr[l2] + sm.scr[128 + l2] + sm.scr[256 + l2] + sm.scr[384 + l2]);
    float v = sm.u12[l] * wa + sm.u12[l2] * wb;
    v = wred_sum(v);
    if (l == 0) {
      const float wyv = -(y1 + v) * u11i;
      if (accum) sm.scal[dy_slot] += wyv; else sm.scal[dy_slot] = wyv;
      sm.scal[SC_WY] = wyv;
    }
  }
  __syncthreads();
  const float wy = sm.scal[SC_WY];
  {  // dx = Qinv g1, g1 inlined from partials (same summation order)
    float acc = 0.0f;
#pragma unroll
    for (int c = 0; c < 8; ++c) {
      const int j = seg * 8 + c;
      float g1v = sm.scr[512 + j] + sm.scr[512 + 64 + j] + sm.scr[512 + 128 + j]
                + sm.scr[512 + 192 + j] - Ab[j] * wy;
      if (has_rx) g1v -= rx[j];
      acc += qreg[c] * g1v;
    }
    acc += __shfl_down(acc, 4); acc += __shfl_down(acc, 2); acc += __shfl_down(acc, 1);
    if (seg == 0) { if (accum) dx_t[o8] += acc; else dx_t[o8] = acc; }
  }
  __syncthreads();
}

__global__ __launch_bounds__(NT, 2)
void optnet_kernel(const float* __restrict__ Qg, const float* __restrict__ pg,
                   const float* __restrict__ Ag, const float* __restrict__ bg,
                   const float* __restrict__ Gg, const float* __restrict__ hg,
                   float* __restrict__ outg) {
  __shared__ Smem sm;
  const int bId = blockIdx.x;
  const int tid = threadIdx.x;
  const float* Qb = Qg + (size_t)bId * 4096;
  const float* pb = pg + (size_t)bId * 64;
  const float* Ab = Ag + (size_t)bId * 64;
  const float  bb = bg[bId];
  const float* Gb = Gg + (size_t)bId * 8192;
  const float* hb = hg + (size_t)bId * 128;

  // ---- pre-factor Q: rank-8 chol + trtri at stride 68 -> V_Q (upper), zero lower
  for (int idx = tid; idx < 4096; idx += NT)
    sm.W[(idx >> 6) * 68 + (idx & 63)] = Qb[idx];
  if (tid < 128) sm.dd[tid] = 1.0f;
  __syncthreads();
  {
    const int tr = tid >> 4, tc = tid & 15;
    const int i0 = tr << 2, j0 = tc << 3;
    const int act = (tr < 16) && (tc < 8);
    float Wt[4][8];
    if (act) {
#pragma unroll
      for (int m = 0; m < 4; ++m)
#pragma unroll
        for (int c = 0; c < 8; ++c)
          Wt[m][c] = sm.W[(i0 + m) * 68 + j0 + c];
    }
    chol_rank8<64, 64, 68>(sm, Wt, act, tid);
    write_U<68>(sm, Wt, act, i0, j0);
  }
  __syncthreads();
  trtri_fast<64, 68>(sm, tid);
  for (int idx = tid; idx < 4096; idx += NT) {
    const int i = idx >> 6, j = idx & 63;
    if (i > j) sm.W[i * 68 + j] = 0.0f;
  }
  __syncthreads();
  // ---- Qinv into registers: thread (o8=tid>>3) holds Qi[o8][8*seg .. +8)
  float qreg[8];
  {
    const int o = tid >> 3, sgq = tid & 7;
#pragma unroll 1
    for (int c = 0; c < 8; ++c) {
      const int j = sgq * 8 + c;
      float acc = 0.0f;
      for (int k = 0; k < 64; ++k) acc += sm.W[o * 68 + k] * sm.W[j * 68 + k];
      qreg[c] = acc;
    }
  }
  // ---- w = V_Q^T a (into t); u11
  if (tid < 64) {
    float acc = 0.0f;
    for (int m = 0; m < 64; ++m) acc += sm.W[m * 68 + tid] * Ab[m];
    sm.t[tid] = acc;
  }
  __syncthreads();
  if (tid < 64) {
    float v = sm.t[tid] * sm.t[tid];
    v = wred_sum(v);
    if (tid == 0) sm.scal[SC_U11I] = 1.0f / sqrtf(v);
  }
  __syncthreads();
  // ---- t1 = V_Q^T G^T (64 x 128): V from LDS, G rows DIRECT from global
  // (no staging, no chunk barriers; lane groups share G addresses -> L1/L2)
  {
    const int kt = tid & 15, jt = tid >> 4;
    const int k0 = kt << 2, j0 = jt << 2;
    float t1a[4][4] = {};
#pragma unroll 1
    for (int m = 0; m < 64; m += 4) {
      const float4 g0 = *(const float4*)&Gb[(j0 + 0) * 64 + m];
      const float4 g1 = *(const float4*)&Gb[(j0 + 1) * 64 + m];
      const float4 g2 = *(const float4*)&Gb[(j0 + 2) * 64 + m];
      const float4 g3 = *(const float4*)&Gb[(j0 + 3) * 64 + m];
      const float gr[4][4] = {{g0.x, g0.y, g0.z, g0.w}, {g1.x, g1.y, g1.z, g1.w},
                              {g2.x, g2.y, g2.z, g2.w}, {g3.x, g3.y, g3.z, g3.w}};
#pragma unroll
      for (int i = 0; i < 4; ++i) {
        const float4 v = *(const float4*)&sm.W[(m + i) * 68 + k0];
        const float vv[4] = {v.x, v.y, v.z, v.w};
#pragma unroll
        for (int a = 0; a < 4; ++a)
#pragma unroll
          for (int b2 = 0; b2 < 4; ++b2)
            t1a[a][b2] = fmaf(vv[a], gr[b2][i], t1a[a][b2]);
      }
    }
#pragma unroll
    for (int a = 0; a < 4; ++a)
      *(float4*)&sm.W[T1O + (k0 + a) * T1S + j0] =
          make_float4(t1a[a][0], t1a[a][1], t1a[a][2], t1a[a][3]);
  }
  __syncthreads();
  // ---- u12 = (t1^T w) * u11i  (split-k over 4 groups)
  {
    const int o = tid & 127, p = tid >> 7;
    float acc = 0.0f;
    for (int k = (p << 4); k < (p << 4) + 16; ++k)
      acc += sm.W[T1O + k * T1S + o] * sm.t[k];
    sm.scr[(p << 7) + o] = acc;
  }
  __syncthreads();
  if (tid < 128)
    sm.u12[tid] = (sm.scr[tid] + sm.scr[128 + tid] + sm.scr[256 + tid] + sm.scr[384 + tid])
                  * sm.scal[SC_U11I];
  __syncthreads();
  // ---- R = t1^T t1 - u12 u12^T: compute tile in (transient) registers ...
  float racc[4][8];
  {
    const int tr = tid >> 4, tc = tid & 15;
    const int i0 = tr << 2, j0 = tc << 3;
#pragma unroll
    for (int m = 0; m < 4; ++m)
#pragma unroll
      for (int c = 0; c < 8; ++c) racc[m][c] = 0.0f;
#pragma unroll 2
    for (int k = 0; k < 64; ++k) {
      const float4 a  = *(const float4*)&sm.W[T1O + k * T1S + i0];
      const float4 b0 = *(const float4*)&sm.W[T1O + k * T1S + j0];
      const float4 b1 = *(const float4*)&sm.W[T1O + k * T1S + j0 + 4];
      const float av[4] = {a.x, a.y, a.z, a.w};
      const float bv[8] = {b0.x, b0.y, b0.z, b0.w, b1.x, b1.y, b1.z, b1.w};
#pragma unroll
      for (int m = 0; m < 4; ++m)
#pragma unroll
        for (int c = 0; c < 8; ++c) racc[m][c] = fmaf(av[m], bv[c], racc[m][c]);
    }
#pragma unroll
    for (int m = 0; m < 4; ++m) {
      const float ui = sm.u12[i0 + m];
#pragma unroll
      for (int c = 0; c < 8; ++c) racc[m][c] -= ui * sm.u12[j0 + c];
    }
  }
  __syncthreads();
  {
    const int tr = tid >> 4, tc = tid & 15;
    const int i0 = tr << 2, j0 = tc << 3;
#pragma unroll
    for (int m = 0; m < 4; ++m) {
      const int i = i0 + m;
#pragma unroll
      for (int c = 0; c < 8; ++c) {
        const int j = j0 + c;
        if (i < j)       sm.W[j * WST + i] = racc[m][c];
        else if (i == j) sm.Rdiag[i] = racc[m][c];
      }
    }
  }
  if (tid < 128) sm.rz[tid] = -hb[tid];
  __syncthreads();

  // ---- initial factor + solve (d = 1)
  factor_S(sm, 1, tid);
  solve_kkt(sm, qreg, Gb, Ab, 1, pb, nullptr, 1, sm.rz, -bb,
            sm.x, sm.s, sm.z, SC_Y, 0, tid);
  // FUSED min+shift: wave 0 owns s, wave 1 owns z (in-wave broadcast)
  if (tid < 64) {
    float v = fminf(sm.s[tid], sm.s[tid + 64]);
    v = wred_min(v);
    v = __shfl(v, 0);
    const float cs = 1.0f - v;
    if (cs > 1.0f) { sm.s[tid] += cs; sm.s[tid + 64] += cs; }
  } else if (tid < 128) {
    const int l = tid - 64;
    float v = fminf(sm.z[l], sm.z[l + 64]);
    v = wred_min(v);
    v = __shfl(v, 0);
    const float cz = 1.0f - v;
    if (cz > 1.0f) { sm.z[l] += cz; sm.z[l + 64] += cz; }
  }
  __syncthreads();

  // ---- 5 IPM iterations
  for (int it = 0; it < 5; ++it) {
    if (tid < 256) {  // rx partials: G^T z + Q x (coalesced column reads)
      const int o = tid & 63, pq = tid >> 6;
      float acc = 0.0f;
      for (int i = (pq << 5); i < (pq << 5) + 32; ++i) acc += Gb[(i << 6) + o] * sm.z[i];
      for (int k = (pq << 4); k < (pq << 4) + 16; ++k) acc += Qb[(k << 6) + o] * sm.x[k];
      sm.scr[(pq << 6) + o] = acc;
    } else {  // rz = G x + s - h (coalesced row dots, 2-lane groups)
      const int l = tid - 256, i = l >> 1, q = l & 1;
      const float* gr = Gb + (i << 6) + (q << 5);
      float acc = 0.0f;
#pragma unroll
      for (int kk = 0; kk < 32; kk += 4) {
        const float4 g4 = *(const float4*)(gr + kk);
        const float4 x4 = *(const float4*)&sm.x[(q << 5) + kk];
        acc += g4.x * x4.x + g4.y * x4.y + g4.z * x4.z + g4.w * x4.w;
      }
      acc += __shfl_down(acc, 1);
      if (q == 0) sm.rz[i] = acc + sm.s[i] - hb[i];
    }
    __syncthreads();
    // FUSED: rxv combine (wave 0) | ry (wave 1) | mu (wave 2) | dd (192..320)
    if (tid < 64) {
      sm.rxv[tid] = pb[tid] + Ab[tid] * sm.scal[SC_Y]
                  + sm.scr[tid] + sm.scr[64 + tid] + sm.scr[128 + tid] + sm.scr[192 + tid];
    } else if (tid < 128) {
      const int l = tid - 64;
      float v = Ab[l] * sm.x[l];
      v = wred_sum(v);
      if (l == 0) sm.scal[SC_RY] = v - bb;
    } else if (tid < 192) {
      const int l = tid - 128;
      float v = sm.s[l] * sm.z[l] + sm.s[l + 64] * sm.z[l + 64];
      v = wred_sum(v);
      if (l == 0) sm.scal[SC_MU] = v * (1.0f / 128.0f);
    } else if (tid < 320) {
      const int i = tid - 192;
      sm.dd[i] = sm.z[i] / sm.s[i];
    }
    __syncthreads();
    factor_S(sm, 0, tid);
    // affine predictor (rs = z)
    solve_kkt(sm, qreg, Gb, Ab, 1, sm.rxv, sm.z, 1, sm.rz, sm.scal[SC_RY],
              sm.dxa, sm.dsa, sm.dza, SC_DYA, 0, tid);
    // FUSED alpha_aff + sigma (wave 0; alpha broadcast in-wave, not published)
    if (tid < 64) {
      float m = __builtin_inff();
#pragma unroll
      for (int rep = 0; rep < 2; ++rep) {
        const int i = tid + 64 * rep;
        m = fminf(m, step_val(sm.z[i], sm.dza[i]));
        m = fminf(m, step_val(sm.s[i], sm.dsa[i]));
      }
      m = wred_min(m);
      float alpha = 0.999f * fminf(m, 1.0f);
      alpha = __shfl(alpha, 0);
      float v = 0.0f;
#pragma unroll
      for (int rep = 0; rep < 2; ++rep) {
        const int i = tid + 64 * rep;
        v += (sm.s[i] + alpha * sm.dsa[i]) * (sm.z[i] + alpha * sm.dza[i]);
      }
      v = wred_sum(v);
      if (tid == 0) {
        const float mu = sm.scal[SC_MU];
        const float r = v / (mu * 128.0f);
        sm.scal[SC_MUSIG] = -mu * r * r * r;
      }
    }
    __syncthreads();
    // non_zero -> rz buffer (rs for corrector) + corrector H = rs/d, H1 = 0
    if (tid < 128) {
      const float v = (sm.scal[SC_MUSIG] + sm.dsa[tid] * sm.dza[tid]) / sm.s[tid];
      sm.rz[tid] = v;
      sm.H[tid] = v / sm.dd[tid];
    } else if (tid == 128) {
      sm.scal[SC_H1] = 0.0f;
    }
    __syncthreads();
    // corrector (light): accumulates into dxa/dsa/dza/SC_DYA
    solve_kkt(sm, qreg, Gb, Ab, 0, nullptr, sm.rz, 0, nullptr, 0.0f,
              sm.dxa, sm.dsa, sm.dza, SC_DYA, 1, tid);
    // FUSED alpha2 + state update (wave 0 does everything)
    if (tid < 64) {
      float m = __builtin_inff();
#pragma unroll
      for (int rep = 0; rep < 2; ++rep) {
        const int i = tid + 64 * rep;
        m = fminf(m, step_val(sm.z[i], sm.dza[i]));
        m = fminf(m, step_val(sm.s[i], sm.dsa[i]));
      }
      m = wred_min(m);
      float a2 = 0.999f * fminf(m, 1.0f);
      a2 = __shfl(a2, 0);
      sm.s[tid]      += a2 * sm.dsa[tid];
      sm.s[tid + 64] += a2 * sm.dsa[tid + 64];
      sm.z[tid]      += a2 * sm.dza[tid];
      sm.z[tid + 64] += a2 * sm.dza[tid + 64];
      sm.x[tid]      += a2 * sm.dxa[tid];
      if (tid == 0) sm.scal[SC_Y] += a2 * sm.scal[SC_DYA];
    }
    __syncthreads();
  }
  if (tid < 64) outg[((size_t)bId << 6) + tid] = sm.x[tid];
}

extern "C" void kernel_launch(void* const* d_in, const int* in_sizes, int n_in,
                              void* d_out, int out_size, void* d_ws, size_t ws_size,
                              hipStream_t stream) {
  (void)n_in; (void)d_ws; (void)ws_size; (void)out_size;
  const float* Q = (const float*)d_in[0];
  const float* p = (const float*)d_in[1];
  const float* A = (const float*)d_in[2];
  const float* b = (const float*)d_in[3];
  const float* G = (const float*)d_in[4];
  const float* h = (const float*)d_in[5];
  const int B = in_sizes[3];  // b has one element per batch
  optnet_kernel<<<B, NT, 0, stream>>>(Q, p, A, b, G, h, (float*)d_out);
}

// Round 6
// 1990.896 us; speedup vs baseline: 1.2338x; 1.2338x over previous
//
#include <hip/hip_runtime.h>
#include <math.h>

// OptNet batched QP IPM solver — Round 12: occupancy attack (LDS < 64 KiB).
// Evidence: OccupancyPercent ~24% (= 8 waves/CU = ONE block resident) in
// EVERY round, and a ~2450us floor insensitive to barrier count (R11: -53
// intervals -> flat) and FLOPs (R10: 2x factor FLOPs -> flat). Theory: with
// LDS 81920 B only one 512-thread block co-resides per CU, so convoy stalls
// have nothing to overlap. Fix: LDS 81920 -> ~56.6 KB so two blocks fit:
//  * R is never stored: t1 (64x128, stride 130) stays in LDS permanently and
//    S = t1^T t1 - u12 u12^T + diag is rebuilt into registers each factor
//    (bitwise-identical each time; same fma order as the old racc loop).
//  * M^{-1} is never materialized: after sweep128, Wt IS -M^{-1}. The solve
//    matvec runs from registers: per-row fma + 16-lane shfl reduce -> Y[].
//    (Wt = -Minv, so wz = -Minv v = +Wt.v : no negation.)
//  * pool layout: [0,4352) V_Q (stride 68) in setup, sweep panels (2048) +
//    g1 partials [2048,2304) in steady state; [4352,12672) t1 (stride 130);
//    Q-path chol panels / trtri Vd use [4352,...) before t1 exists.
// __launch_bounds__(512,4): VGPR <= 128 so 16 waves/CU is register-legal.

#define NT  512
#define T1_O  4352   // t1 = V_Q^T G^T, 64 x 128 at stride 130
#define T1_ST 130    // 130 % 32 = 2 -> 2-way column conflicts (free)
#define GP_O  2048   // g1 partials (256 floats) inside dead V_Q region
#define QP_O  4352   // Q-path chol panel / trtri Vd scratch (pre-t1)

struct __align__(16) Smem {
  float pool[12672];  // 50688 B: V_Q/panels/partials + t1 (see header)
  float x[64], rxv[64], t[64], dxa[64];
  float s[128], z[128], rz[128], dsa[128], dza[128], u12[128], dd[128], H[128], Y[128];
  float scalbuf[64];  // Q-path: [0,16) | sweep: [16,62)
  float scal[16];
};
static_assert(sizeof(Smem) <= 65536, "LDS must be under 64 KiB for 2 blocks/CU");

enum { SC_H1 = 2, SC_U11I = 4, SC_RY = 5, SC_MU = 6,
       SC_MUSIG = 8, SC_Y = 9, SC_DYA = 10, SC_WY = 11 };

__device__ __forceinline__ float wred_sum(float v) {
#pragma unroll
  for (int off = 32; off > 0; off >>= 1) v += __shfl_down(v, off);
  return v;
}
__device__ __forceinline__ float wred_min(float v) {
#pragma unroll
  for (int off = 32; off > 0; off >>= 1) v = fminf(v, __shfl_down(v, off));
  return v;
}
__device__ __forceinline__ float step_val(float v, float dv) {
  float a = -v / dv;
  return (a > 0.0f) ? a : __builtin_inff();  // NaN -> inf (matches ref)
}
__device__ __forceinline__ constexpr int pk16(int i) {  // packed 16x16 upper row start
  return i * 16 - ((i * (i - 1)) >> 1);
}

// ======================= Q-path (64x64) machinery ==========================
// Panels/Vd live at `pan`/`vd` (pool[QP_O..), free until t1 is written).

template<int RW>
__device__ __forceinline__ void elim_publish(Smem& sm, float* pan, float (&Wt)[4][8],
                                             int q, int tc) {
  const int tcd = q >> 1;
  const int co = (q & 1) << 2;
  float L10 = 0, L20 = 0, L30 = 0, L21 = 0, L31 = 0, L32 = 0;
  float id0 = 0, id1 = 0, id2 = 0, id3 = 0;
  if (tc == tcd) {
    float D[4][4];
#pragma unroll
    for (int m = 0; m < 4; ++m)
#pragma unroll
      for (int c = 0; c < 4; ++c) D[m][c] = Wt[m][co + c];
    id0 = 1.0f / D[0][0];
    L10 = D[0][1] * id0; L20 = D[0][2] * id0; L30 = D[0][3] * id0;
#pragma unroll
    for (int c = 0; c < 4; ++c) {
      D[1][c] -= L10 * D[0][c]; D[2][c] -= L20 * D[0][c]; D[3][c] -= L30 * D[0][c];
    }
    id1 = 1.0f / D[1][1];
    L21 = D[1][2] * id1; L31 = D[1][3] * id1;
#pragma unroll
    for (int c = 0; c < 4; ++c) { D[2][c] -= L21 * D[1][c]; D[3][c] -= L31 * D[1][c]; }
    id2 = 1.0f / D[2][2];
    L32 = D[2][3] * id2;
#pragma unroll
    for (int c = 0; c < 4; ++c) D[3][c] -= L32 * D[2][c];
    id3 = 1.0f / D[3][3];
  }
  const int src = ((q & 3) << 4) + tcd;
  L10 = __shfl(L10, src); L20 = __shfl(L20, src); L30 = __shfl(L30, src);
  L21 = __shfl(L21, src); L31 = __shfl(L31, src); L32 = __shfl(L32, src);
#pragma unroll
  for (int c = 0; c < 8; ++c) {
    Wt[1][c] = fmaf(-L10, Wt[0][c], Wt[1][c]);
    Wt[2][c] = fmaf(-L20, Wt[0][c], Wt[2][c]);
    Wt[2][c] = fmaf(-L21, Wt[1][c], Wt[2][c]);
    Wt[3][c] = fmaf(-L30, Wt[0][c], Wt[3][c]);
    Wt[3][c] = fmaf(-L31, Wt[1][c], Wt[3][c]);
    Wt[3][c] = fmaf(-L32, Wt[2][c], Wt[3][c]);
  }
  const int pb = (q >> 1) & 1;
  float* pp = pan + pb * (8 * RW) + (q & 1) * (4 * RW);
  const int j0 = tc << 3;
#pragma unroll
  for (int m = 0; m < 4; ++m) {
    *(float4*)&pp[m * RW + j0]     = make_float4(Wt[m][0], Wt[m][1], Wt[m][2], Wt[m][3]);
    *(float4*)&pp[m * RW + j0 + 4] = make_float4(Wt[m][4], Wt[m][5], Wt[m][6], Wt[m][7]);
  }
  if (tc == tcd) {
    float* sb = sm.scalbuf + pb * 8 + ((q & 1) << 2);
    sb[0] = id0; sb[1] = id1; sb[2] = id2; sb[3] = id3;
    sm.Y[(q << 2) + 0] = id0; sm.Y[(q << 2) + 1] = id1;
    sm.Y[(q << 2) + 2] = id2; sm.Y[(q << 2) + 3] = id3;
  }
}

template<int RW>
__device__ __forceinline__ void apply_panel4(Smem& sm, float* pan, float (&Wt)[4][8],
                                             int pb, int half, int i0, int j0) {
  const float* pp = pan + pb * (8 * RW) + half * (4 * RW);
  const float* sb = sm.scalbuf + pb * 8 + (half << 2);
#pragma unroll 1
  for (int mm = 0; mm < 4; ++mm) {
    const float idm = sb[mm];
    const float4 pv  = *(const float4*)&pp[mm * RW + i0];
    const float4 pj0 = *(const float4*)&pp[mm * RW + j0];
    const float4 pj1 = *(const float4*)&pp[mm * RW + j0 + 4];
    const float um0 = pv.x * idm, um1 = pv.y * idm;
    const float um2 = pv.z * idm, um3 = pv.w * idm;
    const float pjv[8] = {pj0.x, pj0.y, pj0.z, pj0.w, pj1.x, pj1.y, pj1.z, pj1.w};
#pragma unroll
    for (int c = 0; c < 8; ++c) {
      Wt[0][c] = fmaf(-um0, pjv[c], Wt[0][c]);
      Wt[1][c] = fmaf(-um1, pjv[c], Wt[1][c]);
      Wt[2][c] = fmaf(-um2, pjv[c], Wt[2][c]);
      Wt[3][c] = fmaf(-um3, pjv[c], Wt[3][c]);
    }
  }
}

template<int N, int RW, int ST>
__device__ void chol_rank8(Smem& sm, float* pan, float (&Wt)[4][8], int act, int tid) {
  const int tr = tid >> 4, tc = tid & 15;
  const int i0 = tr << 2, j0 = tc << 3;
  constexpr int NP = N / 8;
#pragma unroll 1
  for (int P = 0; P < NP; ++P) {
    const int pb = P & 1;
    if (P > 0 && act && tr >= 2 * P) {
      apply_panel4<RW>(sm, pan, Wt, pb ^ 1, 0, i0, j0);
      apply_panel4<RW>(sm, pan, Wt, pb ^ 1, 1, i0, j0);
    }
    if ((tid >> 6) == (P >> 1)) {
      if (act && tr == 2 * P) elim_publish<RW>(sm, pan, Wt, 2 * P, tc);
      __threadfence_block();
      if (act && tr == 2 * P + 1) {
        apply_panel4<RW>(sm, pan, Wt, pb, 0, i0, j0);
        elim_publish<RW>(sm, pan, Wt, 2 * P + 1, tc);
      }
    }
    __syncthreads();
  }
}

template<int ST>
__device__ __forceinline__ void write_U(Smem& sm, float (&Wt)[4][8], int act,
                                        int i0, int j0) {
  if (act && j0 + 7 >= i0) {
    float sqv[4];
#pragma unroll
    for (int m = 0; m < 4; ++m) sqv[m] = sqrtf(sm.Y[i0 + m]);
    if (j0 >= i0 + 3) {
#pragma unroll
      for (int m = 0; m < 4; ++m)
#pragma unroll
        for (int qq = 0; qq < 4; ++qq)
          *(float2*)&sm.pool[(i0 + m) * ST + j0 + 2 * qq] =
              make_float2(Wt[m][2 * qq] * sqv[m], Wt[m][2 * qq + 1] * sqv[m]);
    } else {
#pragma unroll
      for (int m = 0; m < 4; ++m) {
        const int i = i0 + m;
#pragma unroll
        for (int c = 0; c < 8; ++c) {
          const int j = j0 + c;
          if (j >= i) sm.pool[i * ST + j] = Wt[m][c] * sqv[m];
        }
      }
    }
  }
}

template<int N, int ST>
__device__ void trtri_fast(Smem& sm, float* vd, int tid) {
  constexpr int NB = N >> 4;
  if (tid < NB * 16) {
    const int blk = tid >> 4, c = tid & 15;
    const float* D = sm.pool + (blk << 4) * ST + (blk << 4);
    float vv[16];
#pragma unroll
    for (int i = 15; i >= 0; --i) {
      float acc = 0.0f;
      for (int k = i + 1; k < 16; ++k) acc += D[i * ST + k] * vv[k];
      const float di = D[i * ST + i];
      const float val = (i == c) ? (1.0f / di) : (-acc / di);
      vv[i] = (i <= c) ? val : 0.0f;
    }
#pragma unroll
    for (int i = 0; i < 16; ++i)
      if (i <= c) vd[blk * 136 + pk16(i) + (c - i)] = vv[i];
  }
  __syncthreads();
  constexpr int NROWS = 16 * (NB * (NB - 1) / 2);
  if (tid < NROWS) {
    int J = 1, base = 0;
    while (base + 16 * J <= tid) { base += 16 * J; ++J; }
    const int k = tid - base, Jb = J << 4;
    float u[16], o[16];
    float2* wr = (float2*)&sm.pool[k * ST + Jb];
#pragma unroll
    for (int q = 0; q < 8; ++q) { const float2 v = wr[q]; u[2*q] = v.x; u[2*q+1] = v.y; }
    const float* vdj = vd + J * 136;
#pragma unroll
    for (int c = 0; c < 16; ++c) {
      float acc = 0.0f;
#pragma unroll
      for (int jj = 0; jj <= c; ++jj) acc += u[jj] * vdj[pk16(jj) + (c - jj)];
      o[c] = acc;
    }
#pragma unroll
    for (int q = 0; q < 8; ++q) wr[q] = make_float2(o[2*q], o[2*q+1]);
  } else {
    for (int idx = tid - NROWS; idx < 256; idx += NT - NROWS) {
      const int r = idx >> 4, c2 = idx & 15;
      if (c2 >= r) sm.pool[r * ST + c2] = vd[pk16(r) + (c2 - r)];
    }
  }
  for (int J = 1; J < NB; ++J) {
    __syncthreads();
    const int Jb = J << 4;
    const int nStrip = Jb << 2;
    float acc[4] = {0.0f, 0.0f, 0.0f, 0.0f};
    int wi = 0, wc = 0;
    if (tid < nStrip) {
      wi = tid >> 2; wc = (tid & 3) << 2;
      for (int k = wi; k < Jb; ++k) {
        const float v = sm.pool[wi * ST + k];
        const float2 u0 = *(const float2*)&sm.pool[k * ST + Jb + wc];
        const float2 u1 = *(const float2*)&sm.pool[k * ST + Jb + wc + 2];
        acc[0] = fmaf(v, u0.x, acc[0]); acc[1] = fmaf(v, u0.y, acc[1]);
        acc[2] = fmaf(v, u1.x, acc[2]); acc[3] = fmaf(v, u1.y, acc[3]);
      }
      acc[0] = -acc[0]; acc[1] = -acc[1]; acc[2] = -acc[2]; acc[3] = -acc[3];
    } else if (tid < nStrip + 64) {
      const int l = tid - nStrip;
      const int r = l >> 2; wi = Jb + r; wc = (l & 3) << 2;
      const float* vp = vd + J * 136 + pk16(r) - r;
#pragma unroll
      for (int q = 0; q < 4; ++q) {
        const int c = wc + q;
        acc[q] = (c >= r) ? vp[c] : 0.0f;
      }
    }
    __syncthreads();
    if (tid < nStrip) {
      *(float2*)&sm.pool[wi * ST + Jb + wc]     = make_float2(acc[0], acc[1]);
      *(float2*)&sm.pool[wi * ST + Jb + wc + 2] = make_float2(acc[2], acc[3]);
    } else if (tid < nStrip + 64) {
      const int r = wi - Jb;
#pragma unroll
      for (int q = 0; q < 4; ++q)
        if (wc + q >= r) sm.pool[wi * ST + Jb + wc + q] = acc[q];
    }
  }
  __syncthreads();
}

// ======================= 128-factor: symmetric SWEEP (register-resident) ===
// Panels at pool[0,2048) (dead V_Q region). After the sweep, Wt = -M^{-1}
// (full square tile per thread) and is NEVER written to LDS.

__device__ __forceinline__ void elim_sweep(Smem& sm, float (&Wt)[4][8],
                                           int q, int tc) {
  const int tcd = q >> 1;
  const int co = (q & 1) << 2;
  float L10 = 0, L20 = 0, L30 = 0, L21 = 0, L31 = 0, L32 = 0;
  float id0 = 0, id1 = 0, id2 = 0, id3 = 0;
  if (tc == tcd) {
    float D[4][4];
#pragma unroll
    for (int m = 0; m < 4; ++m)
#pragma unroll
      for (int c = 0; c < 4; ++c) D[m][c] = Wt[m][co + c];
    id0 = 1.0f / D[0][0];
    L10 = D[0][1] * id0; L20 = D[0][2] * id0; L30 = D[0][3] * id0;
#pragma unroll
    for (int c = 0; c < 4; ++c) {
      D[1][c] -= L10 * D[0][c]; D[2][c] -= L20 * D[0][c]; D[3][c] -= L30 * D[0][c];
    }
    id1 = 1.0f / D[1][1];
    L21 = D[1][2] * id1; L31 = D[1][3] * id1;
#pragma unroll
    for (int c = 0; c < 4; ++c) { D[2][c] -= L21 * D[1][c]; D[3][c] -= L31 * D[1][c]; }
    id2 = 1.0f / D[2][2];
    L32 = D[2][3] * id2;
#pragma unroll
    for (int c = 0; c < 4; ++c) D[3][c] -= L32 * D[2][c];
    id3 = 1.0f / D[3][3];
  }
  const int src = ((q & 3) << 4) + tcd;
  L10 = __shfl(L10, src); L20 = __shfl(L20, src); L30 = __shfl(L30, src);
  L21 = __shfl(L21, src); L31 = __shfl(L31, src); L32 = __shfl(L32, src);
  id0 = __shfl(id0, src); id1 = __shfl(id1, src);
  id2 = __shfl(id2, src); id3 = __shfl(id3, src);
#pragma unroll
  for (int c = 0; c < 8; ++c) {  // own rows -> F_raw = L^{-1} * rows
    Wt[1][c] = fmaf(-L10, Wt[0][c], Wt[1][c]);
    Wt[2][c] = fmaf(-L20, Wt[0][c], Wt[2][c]);
    Wt[2][c] = fmaf(-L21, Wt[1][c], Wt[2][c]);
    Wt[3][c] = fmaf(-L30, Wt[0][c], Wt[3][c]);
    Wt[3][c] = fmaf(-L31, Wt[1][c], Wt[3][c]);
    Wt[3][c] = fmaf(-L32, Wt[2][c], Wt[3][c]);
  }
  const int pb = (q >> 1) & 1;
  float* pp = sm.pool + pb * 1024 + (q & 1) * 512;
  const int j0 = tc << 3;
#pragma unroll
  for (int m = 0; m < 4; ++m) {   // publish F_raw (pre-back-sub) panel
    *(float4*)&pp[m * 128 + j0]     = make_float4(Wt[m][0], Wt[m][1], Wt[m][2], Wt[m][3]);
    *(float4*)&pp[m * 128 + j0 + 4] = make_float4(Wt[m][4], Wt[m][5], Wt[m][6], Wt[m][7]);
  }
  if (tc == tcd) {
    float* sb = sm.scalbuf + 16 + pb * 24 + (q & 1) * 12;
    sb[0] = id0; sb[1] = id1; sb[2] = id2; sb[3] = id3;
    sb[4] = L10; sb[5] = L20; sb[6] = L30; sb[7] = L21; sb[8] = L31; sb[9] = L32;
  }
  // own rows -> P^{-1}B = L^{-T} D^{-1} F (back-substitution, per column)
#pragma unroll
  for (int c = 0; c < 8; ++c) {
    const float t3 = id3 * Wt[3][c];
    const float t2 = id2 * Wt[2][c] - L32 * t3;
    const float t1v = id1 * Wt[1][c] - L21 * t2 - L31 * t3;
    const float t0 = id0 * Wt[0][c] - L10 * t1v - L20 * t2 - L30 * t3;
    Wt[0][c] = t0; Wt[1][c] = t1v; Wt[2][c] = t2; Wt[3][c] = t3;
  }
  if (tc == tcd) {  // pivot 4x4 <- -P^{-1} = -(L^{-1})^T D^{-1} L^{-1}
    const float m10 = -L10, m21 = -L21, m32 = -L32;
    const float m20 = -L20 + L21 * L10;
    const float m31 = -L31 + L32 * L21;
    const float m30 = -L30 + L31 * L10 + L32 * L20 - L32 * L21 * L10;
    const float P00 = id0 + id1*m10*m10 + id2*m20*m20 + id3*m30*m30;
    const float P01 = id1*m10 + id2*m20*m21 + id3*m30*m31;
    const float P02 = id2*m20 + id3*m30*m32;
    const float P03 = id3*m30;
    const float P11 = id1 + id2*m21*m21 + id3*m31*m31;
    const float P12 = id2*m21 + id3*m31*m32;
    const float P13 = id3*m31;
    const float P22 = id2 + id3*m32*m32;
    const float P23 = id3*m32;
    const float P33 = id3;
    Wt[0][co+0] = -P00; Wt[0][co+1] = -P01; Wt[0][co+2] = -P02; Wt[0][co+3] = -P03;
    Wt[1][co+0] = -P01; Wt[1][co+1] = -P11; Wt[1][co+2] = -P12; Wt[1][co+3] = -P13;
    Wt[2][co+0] = -P02; Wt[2][co+1] = -P12; Wt[2][co+2] = -P22; Wt[2][co+3] = -P23;
    Wt[3][co+0] = -P03; Wt[3][co+1] = -P13; Wt[3][co+2] = -P23; Wt[3][co+3] = -P33;
  }
}

__device__ __forceinline__ void apply_sweep(Smem& sm, float (&Wt)[4][8],
                                            int q, int i0, int j0, int tr, int tc,
                                            int skip_partner) {
  if (tr == q) return;  // own panel: rows already replaced at elim time
  if (skip_partner && !(q & 1) && tr == q + 1) return;
  const int pb = (q >> 1) & 1;
  const float* pp = sm.pool + pb * 1024 + (q & 1) * 512;
  const float* sb = sm.scalbuf + 16 + pb * 24 + (q & 1) * 12;
#pragma unroll 1
  for (int mm = 0; mm < 4; ++mm) {
    const float idm = sb[mm];
    const float4 pv  = *(const float4*)&pp[mm * 128 + i0];
    const float4 pj0 = *(const float4*)&pp[mm * 128 + j0];
    const float4 pj1 = *(const float4*)&pp[mm * 128 + j0 + 4];
    const float um0 = pv.x * idm, um1 = pv.y * idm;
    const float um2 = pv.z * idm, um3 = pv.w * idm;
    const float pjv[8] = {pj0.x, pj0.y, pj0.z, pj0.w, pj1.x, pj1.y, pj1.z, pj1.w};
#pragma unroll
    for (int c = 0; c < 8; ++c) {
      Wt[0][c] = fmaf(-um0, pjv[c], Wt[0][c]);
      Wt[1][c] = fmaf(-um1, pjv[c], Wt[1][c]);
      Wt[2][c] = fmaf(-um2, pjv[c], Wt[2][c]);
      Wt[3][c] = fmaf(-um3, pjv[c], Wt[3][c]);
    }
  }
  if (tc == (q >> 1)) {  // pivot-column cells: (P^{-1}B)[:, i] via back-sub
    const int co = (q & 1) << 2;
    const float id0 = sb[0], id1 = sb[1], id2 = sb[2], id3 = sb[3];
    const float L10 = sb[4], L20 = sb[5], L30 = sb[6];
    const float L21 = sb[7], L31 = sb[8], L32 = sb[9];
#pragma unroll
    for (int r = 0; r < 4; ++r) {
      const float f0 = pp[0 * 128 + i0 + r];
      const float f1 = pp[1 * 128 + i0 + r];
      const float f2 = pp[2 * 128 + i0 + r];
      const float f3 = pp[3 * 128 + i0 + r];
      const float t3 = id3 * f3;
      const float t2 = id2 * f2 - L32 * t3;
      const float t1v = id1 * f1 - L21 * t2 - L31 * t3;
      const float t0 = id0 * f0 - L10 * t1v - L20 * t2 - L30 * t3;
      Wt[r][co+0] = t0; Wt[r][co+1] = t1v; Wt[r][co+2] = t2; Wt[r][co+3] = t3;
    }
  }
}

__device__ void sweep128(Smem& sm, float (&Wt)[4][8], int tid) {
  const int tr = tid >> 4, tc = tid & 15;
  const int i0 = tr << 2, j0 = tc << 3;
#pragma unroll 1
  for (int P = 0; P < 16; ++P) {
    if (P > 0) {
      apply_sweep(sm, Wt, 2 * P - 2, i0, j0, tr, tc, 1);
      apply_sweep(sm, Wt, 2 * P - 1, i0, j0, tr, tc, 1);
    }
    if ((tid >> 6) == (P >> 1)) {
      if (tr == 2 * P) elim_sweep(sm, Wt, 2 * P, tc);
      __threadfence_block();
      if (tr == 2 * P + 1) {
        apply_sweep(sm, Wt, 2 * P, i0, j0, tr, tc, 0);
        elim_sweep(sm, Wt, 2 * P + 1, tc);
      }
    }
    __syncthreads();
  }
  apply_sweep(sm, Wt, 30, i0, j0, tr, tc, 1);
  apply_sweep(sm, Wt, 31, i0, j0, tr, tc, 1);
}

// ---- rebuild S = t1^T t1 - u12 u12^T + diag(d + eps) into registers.
// Same fma order as the old racc loop -> bitwise-identical every factor
// (mirror cells identical by commutativity of the products). ----
__device__ void rebuild_S(Smem& sm, float (&Wt)[4][8], int init, int tid) {
  const int tr = tid >> 4, tc = tid & 15;
  const int i0 = tr << 2, j0 = tc << 3;
#pragma unroll
  for (int m = 0; m < 4; ++m)
#pragma unroll
    for (int c = 0; c < 8; ++c) Wt[m][c] = 0.0f;
#pragma unroll 2
  for (int k = 0; k < 64; ++k) {
    const float4 a  = *(const float4*)&sm.pool[T1_O + k * T1_ST + i0];
    const float4 b0 = *(const float4*)&sm.pool[T1_O + k * T1_ST + j0];
    const float4 b1 = *(const float4*)&sm.pool[T1_O + k * T1_ST + j0 + 4];
    const float av[4] = {a.x, a.y, a.z, a.w};
    const float bv[8] = {b0.x, b0.y, b0.z, b0.w, b1.x, b1.y, b1.z, b1.w};
#pragma unroll
    for (int m = 0; m < 4; ++m)
#pragma unroll
      for (int c = 0; c < 8; ++c) Wt[m][c] = fmaf(av[m], bv[c], Wt[m][c]);
  }
#pragma unroll
  for (int m = 0; m < 4; ++m) {
    const float ui = sm.u12[i0 + m];
#pragma unroll
    for (int c = 0; c < 8; ++c) Wt[m][c] -= ui * sm.u12[j0 + c];
  }
#pragma unroll
  for (int m = 0; m < 4; ++m) {
    const int i = i0 + m;
    if (i >= j0 && i < j0 + 8) {
      const int c = i - j0;
      const float dval = init ? 1.0f : sm.s[i] / sm.z[i];
      Wt[m][c] = Wt[m][c] + dval + 1e-6f;
    }
  }
}

// ---- KKT solve from the register-resident -M^{-1} (Wt). has_rx=0
// (corrector): t & H phases skipped — H, SC_H1 pre-filled by the caller.
// wz = -Minv(H - u12 y1) = +Wt.(H - u12 y1): per-row fma + 16-lane shfl
// reduce, tc==0 publishes to Y[]. Barriers: 5 (full) / 3 (light). ----
__device__ void solve_kkt(Smem& sm, const float (&Wt)[4][8], const float* qreg,
                          const float* Gb, const float* Ab,
                          int has_rx, const float* rx, const float* rs,
                          int has_rz, const float* rz, float ry,
                          float* dx_t, float* ds_t, float* dz_t, int dy_slot,
                          int accum, int tid) {
  const float u11i = sm.scal[SC_U11I];
  const int o8 = tid >> 3, seg = tid & 7;
  const int tr = tid >> 4, tc = tid & 15;
  const int i0 = tr << 2, j0 = tc << 3;
  if (has_rx) {
    {  // t = Qinv rx via register Qi + 8-lane shfl reduce
      float acc = 0.0f;
#pragma unroll
      for (int c = 0; c < 8; ++c) acc += qreg[c] * rx[seg * 8 + c];
      acc += __shfl_down(acc, 4); acc += __shfl_down(acc, 2); acc += __shfl_down(acc, 1);
      if (seg == 0) sm.t[o8] = acc;
    }
    __syncthreads();
    {  // H = G t + rs/d - rz  (float4 row dots) + fused H1 = a.t - ry
      const int i = tid >> 2, q = tid & 3;
      float acc = 0.0f;
      const float* gr = Gb + (i << 6) + (q << 4);
#pragma unroll
      for (int kk = 0; kk < 16; kk += 4) {
        const float4 g4 = *(const float4*)(gr + kk);
        const float4 t4 = *(const float4*)&sm.t[(q << 4) + kk];
        acc += g4.x * t4.x + g4.y * t4.y + g4.z * t4.z + g4.w * t4.w;
      }
      float h1v = (tid < 64) ? Ab[tid] * sm.t[tid] : 0.0f;
      h1v = wred_sum(h1v);  // meaningful in wave 0 only
      acc += __shfl_down(acc, 2); acc += __shfl_down(acc, 1);
      if (q == 0) {
        if (rs) acc += rs[i] / sm.dd[i];
        if (has_rz) acc -= rz[i];
        sm.H[i] = acc;
      }
      if (tid == 0) sm.scal[SC_H1] = h1v - ry;
    }
    __syncthreads();
  }
  const float y1 = sm.scal[SC_H1] * u11i;
  {  // wz = Wt.(H - u12 y1), row-reduce over the 16-lane tc group -> Y
    float v[8];
#pragma unroll
    for (int c = 0; c < 8; ++c) v[c] = sm.H[j0 + c] - sm.u12[j0 + c] * y1;
#pragma unroll
    for (int m = 0; m < 4; ++m) {
      float p = 0.0f;
#pragma unroll
      for (int c = 0; c < 8; ++c) p = fmaf(Wt[m][c], v[c], p);
      p += __shfl_down(p, 8); p += __shfl_down(p, 4);
      p += __shfl_down(p, 2); p += __shfl_down(p, 1);
      if (tc == 0) sm.Y[i0 + m] = p;
    }
  }
  __syncthreads();
  // FUSED: g1 partials (tid<256) | ds,dz (256..384) | w_y (wave 6) — read Y
  if (tid < 256) {
    const int o = tid & 63, p = tid >> 6;
    float acc = 0.0f;
    for (int i = (p << 5); i < (p << 5) + 32; ++i)
      acc -= Gb[(i << 6) + o] * sm.Y[i];
    sm.pool[GP_O + (p << 6) + o] = acc;
  } else if (tid < 384) {
    const int i = tid - 256;
    const float wzv = sm.Y[i];
    const float r = rs ? rs[i] : 0.0f;
    const float dsv = (-r - wzv) / sm.dd[i];
    if (accum) { ds_t[i] += dsv; dz_t[i] += wzv; }
    else       { ds_t[i] = dsv;  dz_t[i] = wzv; }
  } else if (tid < 448) {
    const int l = tid - 384;
    float vv = sm.u12[l] * sm.Y[l] + sm.u12[l + 64] * sm.Y[l + 64];
    vv = wred_sum(vv);
    if (l == 0) {
      const float wyv = -(y1 + vv) * u11i;
      if (accum) sm.scal[dy_slot] += wyv; else sm.scal[dy_slot] = wyv;
      sm.scal[SC_WY] = wyv;
    }
  }
  __syncthreads();
  const float wy = sm.scal[SC_WY];
  {  // dx = Qinv g1, g1 inlined from partials (same summation order)
    float acc = 0.0f;
#pragma unroll
    for (int c = 0; c < 8; ++c) {
      const int j = seg * 8 + c;
      float g1v = sm.pool[GP_O + j] + sm.pool[GP_O + 64 + j] + sm.pool[GP_O + 128 + j]
                + sm.pool[GP_O + 192 + j] - Ab[j] * wy;
      if (has_rx) g1v -= rx[j];
      acc += qreg[c] * g1v;
    }
    acc += __shfl_down(acc, 4); acc += __shfl_down(acc, 2); acc += __shfl_down(acc, 1);
    if (seg == 0) { if (accum) dx_t[o8] += acc; else dx_t[o8] = acc; }
  }
  __syncthreads();
}

__global__ __launch_bounds__(NT, 4)
void optnet_kernel(const float* __restrict__ Qg, const float* __restrict__ pg,
                   const float* __restrict__ Ag, const float* __restrict__ bg,
                   const float* __restrict__ Gg, const float* __restrict__ hg,
                   float* __restrict__ outg) {
  __shared__ Smem sm;
  const int bId = blockIdx.x;
  const int tid = threadIdx.x;
  const float* Qb = Qg + (size_t)bId * 4096;
  const float* pb = pg + (size_t)bId * 64;
  const float* Ab = Ag + (size_t)bId * 64;
  const float  bb = bg[bId];
  const float* Gb = Gg + (size_t)bId * 8192;
  const float* hb = hg + (size_t)bId * 128;

  // ---- pre-factor Q: rank-8 chol + trtri at stride 68 -> V_Q (upper), zero lower
  for (int idx = tid; idx < 4096; idx += NT)
    sm.pool[(idx >> 6) * 68 + (idx & 63)] = Qb[idx];
  if (tid < 128) sm.dd[tid] = 1.0f;
  __syncthreads();
  {
    const int tr = tid >> 4, tc = tid & 15;
    const int i0 = tr << 2, j0 = tc << 3;
    const int act = (tr < 16) && (tc < 8);
    float Wq[4][8];
    if (act) {
#pragma unroll
      for (int m = 0; m < 4; ++m)
#pragma unroll
        for (int c = 0; c < 8; ++c)
          Wq[m][c] = sm.pool[(i0 + m) * 68 + j0 + c];
    }
    chol_rank8<64, 64, 68>(sm, sm.pool + QP_O, Wq, act, tid);
    write_U<68>(sm, Wq, act, i0, j0);
  }
  __syncthreads();
  trtri_fast<64, 68>(sm, sm.pool + QP_O, tid);
  for (int idx = tid; idx < 4096; idx += NT) {
    const int i = idx >> 6, j = idx & 63;
    if (i > j) sm.pool[i * 68 + j] = 0.0f;
  }
  __syncthreads();
  // ---- Qinv into registers: thread (o8=tid>>3) holds Qi[o8][8*seg .. +8)
  float qreg[8];
  {
    const int o = tid >> 3, sgq = tid & 7;
#pragma unroll 1
    for (int c = 0; c < 8; ++c) {
      const int j = sgq * 8 + c;
      float acc = 0.0f;
      for (int k = 0; k < 64; ++k) acc += sm.pool[o * 68 + k] * sm.pool[j * 68 + k];
      qreg[c] = acc;
    }
  }
  // ---- w = V_Q^T a (into t); u11
  if (tid < 64) {
    float acc = 0.0f;
    for (int m = 0; m < 64; ++m) acc += sm.pool[m * 68 + tid] * Ab[m];
    sm.t[tid] = acc;
  }
  __syncthreads();
  if (tid < 64) {
    float v = sm.t[tid] * sm.t[tid];
    v = wred_sum(v);
    if (tid == 0) sm.scal[SC_U11I] = 1.0f / sqrtf(v);
  }
  __syncthreads();
  // ---- t1 = V_Q^T G^T (64 x 128): V from LDS, G rows DIRECT from global
  {
    const int kt = tid & 15, jt = tid >> 4;
    const int k0 = kt << 2, j0 = jt << 2;
    float t1a[4][4] = {};
#pragma unroll 1
    for (int m = 0; m < 64; m += 4) {
      const float4 g0 = *(const float4*)&Gb[(j0 + 0) * 64 + m];
      const float4 g1 = *(const float4*)&Gb[(j0 + 1) * 64 + m];
      const float4 g2 = *(const float4*)&Gb[(j0 + 2) * 64 + m];
      const float4 g3 = *(const float4*)&Gb[(j0 + 3) * 64 + m];
      const float gr[4][4] = {{g0.x, g0.y, g0.z, g0.w}, {g1.x, g1.y, g1.z, g1.w},
                              {g2.x, g2.y, g2.z, g2.w}, {g3.x, g3.y, g3.z, g3.w}};
#pragma unroll
      for (int i = 0; i < 4; ++i) {
        const float4 v = *(const float4*)&sm.pool[(m + i) * 68 + k0];
        const float vv[4] = {v.x, v.y, v.z, v.w};
#pragma unroll
        for (int a = 0; a < 4; ++a)
#pragma unroll
          for (int b2 = 0; b2 < 4; ++b2)
            t1a[a][b2] = fmaf(vv[a], gr[b2][i], t1a[a][b2]);
      }
    }
#pragma unroll
    for (int a = 0; a < 4; ++a)
      *(float4*)&sm.pool[T1_O + (k0 + a) * T1_ST + j0] =
          make_float4(t1a[a][0], t1a[a][1], t1a[a][2], t1a[a][3]);
  }
  __syncthreads();
  // ---- u12 = (t1^T w) * u11i  (split-k over 4 groups; partials in dead V_Q)
  {
    const int o = tid & 127, p = tid >> 7;
    float acc = 0.0f;
    for (int k = (p << 4); k < (p << 4) + 16; ++k)
      acc += sm.pool[T1_O + k * T1_ST + o] * sm.t[k];
    sm.pool[(p << 7) + o] = acc;
  }
  __syncthreads();
  // FUSED: u12 combine (tid<128) | rz = -h (128..256)
  if (tid < 128) {
    sm.u12[tid] = (sm.pool[tid] + sm.pool[128 + tid] + sm.pool[256 + tid] + sm.pool[384 + tid])
                  * sm.scal[SC_U11I];
  } else if (tid < 256) {
    sm.rz[tid - 128] = -hb[tid - 128];
  }
  __syncthreads();

  // ---- register-resident factor tile (lives across factor + both solves)
  float Wt[4][8];

  // ---- initial factor + solve (d = 1)
  rebuild_S(sm, Wt, 1, tid);
  sweep128(sm, Wt, tid);
  solve_kkt(sm, Wt, qreg, Gb, Ab, 1, pb, nullptr, 1, sm.rz, -bb,
            sm.x, sm.s, sm.z, SC_Y, 0, tid);
  // FUSED min+shift: wave 0 owns s, wave 1 owns z (in-wave broadcast)
  if (tid < 64) {
    float v = fminf(sm.s[tid], sm.s[tid + 64]);
    v = wred_min(v);
    v = __shfl(v, 0);
    const float cs = 1.0f - v;
    if (cs > 1.0f) { sm.s[tid] += cs; sm.s[tid + 64] += cs; }
  } else if (tid < 128) {
    const int l = tid - 64;
    float v = fminf(sm.z[l], sm.z[l + 64]);
    v = wred_min(v);
    v = __shfl(v, 0);
    const float cz = 1.0f - v;
    if (cz > 1.0f) { sm.z[l] += cz; sm.z[l + 64] += cz; }
  }
  __syncthreads();

  // ---- 5 IPM iterations
  for (int it = 0; it < 5; ++it) {
    if (tid < 256) {  // rx partials: G^T z + Q x (coalesced column reads)
      const int o = tid & 63, pq = tid >> 6;
      float acc = 0.0f;
      for (int i = (pq << 5); i < (pq << 5) + 32; ++i) acc += Gb[(i << 6) + o] * sm.z[i];
      for (int k = (pq << 4); k < (pq << 4) + 16; ++k) acc += Qb[(k << 6) + o] * sm.x[k];
      sm.pool[GP_O + (pq << 6) + o] = acc;
    } else {  // rz = G x + s - h (coalesced row dots, 2-lane groups)
      const int l = tid - 256, i = l >> 1, q = l & 1;
      const float* gr = Gb + (i << 6) + (q << 5);
      float acc = 0.0f;
#pragma unroll
      for (int kk = 0; kk < 32; kk += 4) {
        const float4 g4 = *(const float4*)(gr + kk);
        const float4 x4 = *(const float4*)&sm.x[(q << 5) + kk];
        acc += g4.x * x4.x + g4.y * x4.y + g4.z * x4.z + g4.w * x4.w;
      }
      acc += __shfl_down(acc, 1);
      if (q == 0) sm.rz[i] = acc + sm.s[i] - hb[i];
    }
    __syncthreads();
    // FUSED: rxv combine (wave 0) | ry (wave 1) | mu (wave 2) | dd (192..320)
    if (tid < 64) {
      sm.rxv[tid] = pb[tid] + Ab[tid] * sm.scal[SC_Y]
                  + sm.pool[GP_O + tid] + sm.pool[GP_O + 64 + tid]
                  + sm.pool[GP_O + 128 + tid] + sm.pool[GP_O + 192 + tid];
    } else if (tid < 128) {
      const int l = tid - 64;
      float v = Ab[l] * sm.x[l];
      v = wred_sum(v);
      if (l == 0) sm.scal[SC_RY] = v - bb;
    } else if (tid < 192) {
      const int l = tid - 128;
      float v = sm.s[l] * sm.z[l] + sm.s[l + 64] * sm.z[l + 64];
      v = wred_sum(v);
      if (l == 0) sm.scal[SC_MU] = v * (1.0f / 128.0f);
    } else if (tid < 320) {
      const int i = tid - 192;
      sm.dd[i] = sm.z[i] / sm.s[i];
    }
    __syncthreads();
    rebuild_S(sm, Wt, 0, tid);
    sweep128(sm, Wt, tid);
    // affine predictor (rs = z)
    solve_kkt(sm, Wt, qreg, Gb, Ab, 1, sm.rxv, sm.z, 1, sm.rz, sm.scal[SC_RY],
              sm.dxa, sm.dsa, sm.dza, SC_DYA, 0, tid);
    // FUSED alpha_aff + sigma (wave 0; alpha broadcast in-wave, not published)
    if (tid < 64) {
      float m = __builtin_inff();
#pragma unroll
      for (int rep = 0; rep < 2; ++rep) {
        const int i = tid + 64 * rep;
        m = fminf(m, step_val(sm.z[i], sm.dza[i]));
        m = fminf(m, step_val(sm.s[i], sm.dsa[i]));
      }
      m = wred_min(m);
      float alpha = 0.999f * fminf(m, 1.0f);
      alpha = __shfl(alpha, 0);
      float v = 0.0f;
#pragma unroll
      for (int rep = 0; rep < 2; ++rep) {
        const int i = tid + 64 * rep;
        v += (sm.s[i] + alpha * sm.dsa[i]) * (sm.z[i] + alpha * sm.dza[i]);
      }
      v = wred_sum(v);
      if (tid == 0) {
        const float mu = sm.scal[SC_MU];
        const float r = v / (mu * 128.0f);
        sm.scal[SC_MUSIG] = -mu * r * r * r;
      }
    }
    __syncthreads();
    // non_zero -> rz buffer (rs for corrector) + corrector H = rs/d, H1 = 0
    if (tid < 128) {
      const float v = (sm.scal[SC_MUSIG] + sm.dsa[tid] * sm.dza[tid]) / sm.s[tid];
      sm.rz[tid] = v;
      sm.H[tid] = v / sm.dd[tid];
    } else if (tid == 128) {
      sm.scal[SC_H1] = 0.0f;
    }
    __syncthreads();
    // corrector (light): accumulates into dxa/dsa/dza/SC_DYA
    solve_kkt(sm, Wt, qreg, Gb, Ab, 0, nullptr, sm.rz, 0, nullptr, 0.0f,
              sm.dxa, sm.dsa, sm.dza, SC_DYA, 1, tid);
    // FUSED alpha2 + state update (wave 0 does everything)
    if (tid < 64) {
      float m = __builtin_inff();
#pragma unroll
      for (int rep = 0; rep < 2; ++rep) {
        const int i = tid + 64 * rep;
        m = fminf(m, step_val(sm.z[i], sm.dza[i]));
        m = fminf(m, step_val(sm.s[i], sm.dsa[i]));
      }
      m = wred_min(m);
      float a2 = 0.999f * fminf(m, 1.0f);
      a2 = __shfl(a2, 0);
      sm.s[tid]      += a2 * sm.dsa[tid];
      sm.s[tid + 64] += a2 * sm.dsa[tid + 64];
      sm.z[tid]      += a2 * sm.dza[tid];
      sm.z[tid + 64] += a2 * sm.dza[tid + 64];
      sm.x[tid]      += a2 * sm.dxa[tid];
      if (tid == 0) sm.scal[SC_Y] += a2 * sm.scal[SC_DYA];
    }
    __syncthreads();
  }
  if (tid < 64) outg[((size_t)bId << 6) + tid] = sm.x[tid];
}

extern "C" void kernel_launch(void* const* d_in, const int* in_sizes, int n_in,
                              void* d_out, int out_size, void* d_ws, size_t ws_size,
                              hipStream_t stream) {
  (void)n_in; (void)d_ws; (void)ws_size; (void)out_size;
  const float* Q = (const float*)d_in[0];
  const float* p = (const float*)d_in[1];
  const float* A = (const float*)d_in[2];
  const float* b = (const float*)d_in[3];
  const float* G = (const float*)d_in[4];
  const float* h = (const float*)d_in[5];
  const int B = in_sizes[3];  // b has one element per batch
  optnet_kernel<<<B, NT, 0, stream>>>(Q, p, A, b, G, h, (float*)d_out);
}